// Round 1
// baseline (593.353 us; speedup 1.0000x reference)
//
#include <hip/hip_runtime.h>
#include <cstdint>
#include <cstddef>
#include <cmath>

typedef __bf16 bf16_t;
typedef __bf16 bf16x8 __attribute__((ext_vector_type(8)));
typedef float floatx4 __attribute__((ext_vector_type(4)));

#define AS1 __attribute__((address_space(1)))
#define AS3 __attribute__((address_space(3)))

__device__ __forceinline__ void gload_lds16(const bf16_t* g, bf16_t* l) {
    __builtin_amdgcn_global_load_lds((AS1 void*)(uintptr_t)(g), (AS3 void*)(l), 16, 0, 0);
}

// ---------------- GEMM: C(M,N) = A(M,K) * B(N,K)^T + bias(N) ----------------
// Grid: (N/128, M/128), 256 threads. M%128==0, N%128==0, K%64==0.
// A,B bf16 row-major; C fp32. m97-style: 128x128 tile, 16x16x32 bf16 MFMA,
// global_load_lds width=16 staging, 2-barrier K-loop.
__global__ __launch_bounds__(256, 2)
void gemm_bt(const bf16_t* __restrict__ A, const bf16_t* __restrict__ B,
             const float* __restrict__ bias, float* __restrict__ C,
             int K, int ldA, int ldB, int ldC)
{
    __shared__ bf16_t As[128 * 64];
    __shared__ bf16_t Bs[128 * 64];
    const int tid  = threadIdx.x;
    const int lane = tid & 63;
    const int w    = tid >> 6;           // wave 0..3
    const int wm   = (w & 1) * 64;       // wave row offset in tile
    const int wn   = (w >> 1) * 64;      // wave col offset in tile
    const int m0   = blockIdx.y * 128;
    const int n0   = blockIdx.x * 128;

    floatx4 zero = {0.0f, 0.0f, 0.0f, 0.0f};
    floatx4 acc[4][4];
#pragma unroll
    for (int i = 0; i < 4; ++i)
#pragma unroll
        for (int j = 0; j < 4; ++j) acc[i][j] = zero;

    const int srow = lane >> 3;          // 0..7   (staging row-in-chunk)
    const int scol = (lane & 7) * 8;     // 0..56  (staging col, 8 bf16 = 16B)
    const int fr   = lane & 15;          // fragment row
    const int fk   = (lane >> 4) * 8;    // fragment k offset

    const bf16_t* Ag = A + (size_t)m0 * ldA + scol;
    const bf16_t* Bg = B + (size_t)n0 * ldB + scol;

    for (int k0 = 0; k0 < K; k0 += 64) {
        __syncthreads();                 // prior compute done before overwrite
#pragma unroll
        for (int j = 0; j < 4; ++j) {
            int r = (w * 4 + j) * 8 + srow;   // 0..127, wave w stages rows w*32..w*32+31
            gload_lds16(Ag + (size_t)r * ldA + k0, As + r * 64 + scol);
            gload_lds16(Bg + (size_t)r * ldB + k0, Bs + r * 64 + scol);
        }
        __syncthreads();                 // drains vmcnt(0): LDS valid
#pragma unroll
        for (int kk = 0; kk < 64; kk += 32) {
            bf16x8 af[4], bfr[4];
#pragma unroll
            for (int i = 0; i < 4; ++i)
                af[i] = *(const bf16x8*)(As + (wm + i * 16 + fr) * 64 + kk + fk);
#pragma unroll
            for (int j = 0; j < 4; ++j)
                bfr[j] = *(const bf16x8*)(Bs + (wn + j * 16 + fr) * 64 + kk + fk);
#pragma unroll
            for (int i = 0; i < 4; ++i)
#pragma unroll
                for (int j = 0; j < 4; ++j)
                    acc[i][j] = __builtin_amdgcn_mfma_f32_16x16x32_bf16(af[i], bfr[j], acc[i][j], 0, 0, 0);
        }
    }

    // C/D layout (m89/m91 verified): col = lane&15, row = (lane>>4)*4 + reg
    const int crow = (lane >> 4) * 4;
    const int ccol = lane & 15;
#pragma unroll
    for (int j = 0; j < 4; ++j) {
        int gn = n0 + wn + j * 16 + ccol;
        float bs = bias[gn];
#pragma unroll
        for (int i = 0; i < 4; ++i) {
            int gm = m0 + wm + i * 16 + crow;
            float* cp = C + (size_t)gm * ldC + gn;
#pragma unroll
            for (int r = 0; r < 4; ++r)
                cp[(size_t)r * ldC] = acc[i][j][r] + bs;
        }
    }
}

// ---------------- LSTM elementwise ----------------
__device__ __forceinline__ float sigf(float x) { return 1.0f / (1.0f + __expf(-x)); }
__device__ __forceinline__ float tanhfast(float x) { return 1.0f - 2.0f / (__expf(2.0f * x) + 1.0f); }

// gates G: (4096 x 4096 fp32), valid cols [i(0:1000) f(1000:2000) g(2000:3000) o(3000:4000)]
// c: (4096 x 1000). h written as bf16 into hdst[row*1152 + j] (A_enc h-slot or A_dec x-slot).
__global__ void lstm_cell_enc(const float* __restrict__ G, float* __restrict__ c,
                              bf16_t* __restrict__ hdst, int relu)
{
    int idx = blockIdx.x * 256 + threadIdx.x;   // 4096*1000 exact
    int row = idx / 1000;
    int j   = idx - row * 1000;
    const float* g = G + (size_t)row * 4096;
    float iv = g[j], fv = g[1000 + j], gv = g[2000 + j], ov = g[3000 + j];
    float cv = sigf(fv) * c[idx] + sigf(iv) * tanhfast(gv);
    float hv = sigf(ov) * tanhfast(cv);
    c[idx] = cv;
    if (relu) hv = fmaxf(hv, 0.0f);
    hdst[(size_t)row * 1152 + j] = (bf16_t)hv;
}

// gates G: (4096 x 512 fp32), valid cols [i(0:101) f(101:202) g(202:303) o(303:404)]
// c: (4096 x 101). If hbf != null: write bf16 h into hbf[row*1152+j]; else fp32 into hf.
__global__ void lstm_cell_dec(const float* __restrict__ G, float* __restrict__ c,
                              bf16_t* __restrict__ hbf, float* __restrict__ hf)
{
    int idx = blockIdx.x * 256 + threadIdx.x;   // 4096*101 exact
    int row = idx / 101;
    int j   = idx - row * 101;
    const float* g = G + (size_t)row * 512;
    float iv = g[j], fv = g[101 + j], gv = g[202 + j], ov = g[303 + j];
    float cv = sigf(fv) * c[idx] + sigf(iv) * tanhfast(gv);
    float hv = sigf(ov) * tanhfast(cv);
    c[idx] = cv;
    if (hbf) hbf[(size_t)row * 1152 + j] = (bf16_t)hv;
    else     hf[idx] = hv;
}

// ---------------- Packing / casting ----------------
// A_enc layout (4096 x 1152 bf16): [x(0:101) pad(101:128) h(128:1128) pad(1128:1152)]
// A_dec layout (4096 x 1152 bf16): [enc(0:1000) pad(1000:1024) h(1024:1125) pad(1125:1152)]
__global__ void pack_x(const float* __restrict__ x, bf16_t* __restrict__ Aenc)
{
    int row = blockIdx.x;      // 4096
    int cx  = threadIdx.x;     // 128
    if (cx < 101)
        Aenc[(size_t)row * 1152 + cx] = (bf16_t)x[row * 101 + cx];
}

// W_enc: per layer 4096 rows x 1152 cols; row r<4000: [Wih_l[r](0:101) 0 Whh_l[r](128:1128) 0]
__global__ void pack_wenc(const float* __restrict__ Wih, const float* __restrict__ Whh,
                          bf16_t* __restrict__ W)
{
    int c   = blockIdx.x * 256 + threadIdx.x;
    int row = blockIdx.y;             // 0..16383
    if (c >= 1152) return;
    int l = row >> 12, r = row & 4095;
    float v = 0.0f;
    if (r < 4000) {
        if (c < 101)                    v = Wih[((size_t)l * 4000 + r) * 101 + c];
        else if (c >= 128 && c < 1128)  v = Whh[((size_t)l * 4000 + r) * 1000 + (c - 128)];
    }
    W[(size_t)row * 1152 + c] = (bf16_t)v;
}

// W_dec: per layer 512 rows x 1152 cols; row r<404: [dWih_l[r](0:1000) 0 dWhh_l[r](1024:1125) 0]
__global__ void pack_wdec(const float* __restrict__ Wih, const float* __restrict__ Whh,
                          bf16_t* __restrict__ W)
{
    int c   = blockIdx.x * 256 + threadIdx.x;
    int row = blockIdx.y;             // 0..2047
    if (c >= 1152) return;
    int l = row >> 9, r = row & 511;
    float v = 0.0f;
    if (r < 404) {
        if (c < 1000)                    v = Wih[((size_t)l * 404 + r) * 1000 + c];
        else if (c >= 1024 && c < 1125)  v = Whh[((size_t)l * 404 + r) * 101 + (c - 1024)];
    }
    W[(size_t)row * 1152 + c] = (bf16_t)v;
}

__global__ void pack_be(const float* __restrict__ bih, const float* __restrict__ bhh,
                        float* __restrict__ b)
{
    int idx = blockIdx.x * 256 + threadIdx.x;  // 16384
    int l = idx >> 12, n = idx & 4095;
    b[idx] = (n < 4000) ? (bih[l * 4000 + n] + bhh[l * 4000 + n]) : 0.0f;
}

__global__ void pack_bd(const float* __restrict__ bih, const float* __restrict__ bhh,
                        float* __restrict__ b)
{
    int idx = blockIdx.x * 256 + threadIdx.x;  // 2048
    int l = idx >> 9, n = idx & 511;
    b[idx] = (n < 404) ? (bih[l * 404 + n] + bhh[l * 404 + n]) : 0.0f;
}

// ---------------- log_softmax over 101 cols, one wave per row ----------------
__global__ void log_softmax_k(const float* __restrict__ h, float* __restrict__ out)
{
    int row = blockIdx.x;
    int l   = threadIdx.x;          // 64
    const float* hr = h + (size_t)row * 101;
    float v1 = (l < 101)      ? hr[l]      : -INFINITY;
    float v2 = (l + 64 < 101) ? hr[l + 64] : -INFINITY;
    float m = fmaxf(v1, v2);
#pragma unroll
    for (int off = 32; off > 0; off >>= 1) m = fmaxf(m, __shfl_down(m, off));
    m = __shfl(m, 0);
    float e = ((l < 101) ? __expf(v1 - m) : 0.0f) + ((l + 64 < 101) ? __expf(v2 - m) : 0.0f);
#pragma unroll
    for (int off = 32; off > 0; off >>= 1) e += __shfl_down(e, off);
    float lse = m + __logf(__shfl(e, 0));
    float* orow = out + (size_t)row * 101;
    if (l < 101)      orow[l]      = v1 - lse;
    if (l + 64 < 101) orow[l + 64] = v2 - lse;
}

extern "C" void kernel_launch(void* const* d_in, const int* in_sizes, int n_in,
                              void* d_out, int out_size, void* d_ws, size_t ws_size,
                              hipStream_t stream)
{
    (void)in_sizes; (void)n_in; (void)out_size; (void)ws_size;
    const float* x    = (const float*)d_in[0];
    const float* eWih = (const float*)d_in[1];
    const float* eWhh = (const float*)d_in[2];
    const float* ebih = (const float*)d_in[3];
    const float* ebhh = (const float*)d_in[4];
    const float* dWih = (const float*)d_in[5];
    const float* dWhh = (const float*)d_in[6];
    const float* dbih = (const float*)d_in[7];
    const float* dbhh = (const float*)d_in[8];

    char* ws = (char*)d_ws;
    bf16_t* Aenc  = (bf16_t*)(ws);                 // 4096*1152*2   =  9,437,184
    bf16_t* Wenc  = (bf16_t*)(ws + 9437184);       // 4*4096*1152*2 = 37,748,736
    bf16_t* Adec  = (bf16_t*)(ws + 47185920);      //                  9,437,184
    bf16_t* Wdec  = (bf16_t*)(ws + 56623104);      // 4*512*1152*2  =  4,718,592
    float*  bse   = (float*) (ws + 61341696);      // 4*4096*4      =     65,536
    float*  bsd   = (float*) (ws + 61407232);      // 4*512*4       =      8,192
    float*  cenc  = (float*) (ws + 61415424);      // 4096*1000*4   = 16,384,000
    float*  cdec  = (float*) (ws + 77799424);      // 4096*101*4    =  1,654,784
    float*  hdec  = (float*) (ws + 79454208);      //                  1,654,784
    float*  gates = (float*) (ws + 81108992);      // 4096*4096*4   = 67,108,864  (end 148,217,856)

    // ws is re-poisoned 0xAA before every call: zero h/c and pad regions.
    hipMemsetAsync(Aenc, 0, 9437184, stream);
    hipMemsetAsync(Adec, 0, 9437184, stream);
    hipMemsetAsync(cenc, 0, 16384000, stream);
    hipMemsetAsync(cdec, 0, 1654784, stream);

    pack_x   <<<4096, 128, 0, stream>>>(x, Aenc);
    pack_wenc<<<dim3(5, 16384), 256, 0, stream>>>(eWih, eWhh, Wenc);
    pack_wdec<<<dim3(5, 2048),  256, 0, stream>>>(dWih, dWhh, Wdec);
    pack_be  <<<64, 256, 0, stream>>>(ebih, ebhh, bse);
    pack_bd  <<<8,  256, 0, stream>>>(dbih, dbhh, bsd);

    // Encoder: 4 layers, gates = [x|h] @ [Wih|Whh]^T + b
    for (int l = 0; l < 4; ++l) {
        gemm_bt<<<dim3(32, 32), 256, 0, stream>>>(
            Aenc, Wenc + (size_t)l * 4096 * 1152, bse + l * 4096, gates,
            1152, 1152, 1152, 4096);
        lstm_cell_enc<<<16000, 256, 0, stream>>>(
            gates, cenc, (l < 3) ? (Aenc + 128) : Adec, (l == 3) ? 1 : 0);
    }
    // Decoder: 4 layers, gates = [enc|h] @ [dWih|dWhh]^T + b
    for (int l = 0; l < 4; ++l) {
        gemm_bt<<<dim3(4, 32), 256, 0, stream>>>(
            Adec, Wdec + (size_t)l * 512 * 1152, bsd + l * 512, gates,
            1152, 1152, 1152, 512);
        lstm_cell_dec<<<1616, 256, 0, stream>>>(
            gates, cdec,
            (l < 3) ? (Adec + 1024) : (bf16_t*)nullptr,
            (l == 3) ? hdec : (float*)nullptr);
    }
    log_softmax_k<<<4096, 64, 0, stream>>>(hdec, (float*)d_out);
}

// Round 2
// 546.679 us; speedup vs baseline: 1.0854x; 1.0854x over previous
//
#include <hip/hip_runtime.h>
#include <cstdint>
#include <cstddef>
#include <cmath>

typedef __bf16 bf16_t;
typedef __bf16 bf16x8 __attribute__((ext_vector_type(8)));
typedef float floatx4 __attribute__((ext_vector_type(4)));

#define AS1 __attribute__((address_space(1)))
#define AS3 __attribute__((address_space(3)))

__device__ __forceinline__ void gload_lds16(const bf16_t* g, bf16_t* l) {
    __builtin_amdgcn_global_load_lds((AS1 void*)(uintptr_t)(g), (AS3 void*)(l), 16, 0, 0);
}

__device__ __forceinline__ float sigf(float x) { return 1.0f / (1.0f + __expf(-x)); }
__device__ __forceinline__ float tanhfast(float x) { return 1.0f - 2.0f / (__expf(2.0f * x) + 1.0f); }

// ------------- Fused GEMM + LSTM cell -------------
// gates(M x N) = A(M,K) @ W(N,K)^T + bias(N), then LSTM cell per element.
// Weight rows are packed interleaved: within each 64-wide N-group `eb`,
// position g*16+ei holds gate g (i,f,g,o) of element e = eb*16+ei.
// => each lane's acc[i][0..3] are the 4 gates of one element column:
//      e = ((n0+wn)>>2) + (lane&15),  rows t = m0+wm+i*16+(lane>>4)*4+r
// c: fp32 (M x EP). h -> either bf16 into hb[t*ldH + hoff + e] (next layer's
// A slot) or fp32 into hf[t*EP + e]. Pad elements have all-zero W rows and
// bias and zero-initialized c => h = 0 is written, keeping pads clean.
__global__ __launch_bounds__(256, 2)
void gemm_lstm(const bf16_t* __restrict__ A, const bf16_t* __restrict__ B,
               const float* __restrict__ bias, float* __restrict__ c, int EP,
               bf16_t* __restrict__ hb, int ldH, int hoff, float* __restrict__ hf,
               int K, int ldA, int ldB, int relu)
{
    __shared__ bf16_t As[128 * 64];
    __shared__ bf16_t Bs[128 * 64];
    const int tid  = threadIdx.x;
    const int lane = tid & 63;
    const int w    = tid >> 6;
    const int wm   = (w & 1) * 64;
    const int wn   = (w >> 1) * 64;
    const int m0   = blockIdx.y * 128;
    const int n0   = blockIdx.x * 128;

    floatx4 zero = {0.0f, 0.0f, 0.0f, 0.0f};
    floatx4 acc[4][4];
#pragma unroll
    for (int i = 0; i < 4; ++i)
#pragma unroll
        for (int j = 0; j < 4; ++j) acc[i][j] = zero;

    const int srow = lane >> 3;
    const int scol = (lane & 7) * 8;
    const int fr   = lane & 15;
    const int fk   = (lane >> 4) * 8;

    const bf16_t* Ag = A + (size_t)m0 * ldA + scol;
    const bf16_t* Bg = B + (size_t)n0 * ldB + scol;

    for (int k0 = 0; k0 < K; k0 += 64) {
        __syncthreads();
#pragma unroll
        for (int j = 0; j < 4; ++j) {
            int r = (w * 4 + j) * 8 + srow;
            gload_lds16(Ag + (size_t)r * ldA + k0, As + r * 64 + scol);
            gload_lds16(Bg + (size_t)r * ldB + k0, Bs + r * 64 + scol);
        }
        __syncthreads();
#pragma unroll
        for (int kk = 0; kk < 64; kk += 32) {
            bf16x8 af[4], bfr[4];
#pragma unroll
            for (int i = 0; i < 4; ++i)
                af[i] = *(const bf16x8*)(As + (wm + i * 16 + fr) * 64 + kk + fk);
#pragma unroll
            for (int j = 0; j < 4; ++j)
                bfr[j] = *(const bf16x8*)(Bs + (wn + j * 16 + fr) * 64 + kk + fk);
#pragma unroll
            for (int i = 0; i < 4; ++i)
#pragma unroll
                for (int j = 0; j < 4; ++j)
                    acc[i][j] = __builtin_amdgcn_mfma_f32_16x16x32_bf16(af[i], bfr[j], acc[i][j], 0, 0, 0);
        }
    }

    // Fused LSTM epilogue. C/D layout: col = lane&15, row = (lane>>4)*4 + reg.
    const int crow = (lane >> 4) * 4;
    const int ccol = lane & 15;
    const int e    = ((n0 + wn) >> 2) + ccol;   // element column for this lane
    float bi[4];
#pragma unroll
    for (int j = 0; j < 4; ++j) bi[j] = bias[n0 + wn + j * 16 + ccol];

#pragma unroll
    for (int i = 0; i < 4; ++i) {
#pragma unroll
        for (int r = 0; r < 4; ++r) {
            int t = m0 + wm + i * 16 + crow + r;
            float iv = acc[i][0][r] + bi[0];
            float fv = acc[i][1][r] + bi[1];
            float gv = acc[i][2][r] + bi[2];
            float ov = acc[i][3][r] + bi[3];
            size_t cix = (size_t)t * EP + e;
            float cv = sigf(fv) * c[cix] + sigf(iv) * tanhfast(gv);
            c[cix] = cv;
            float hv = sigf(ov) * tanhfast(cv);
            if (relu) hv = fmaxf(hv, 0.0f);
            if (hb) hb[(size_t)t * ldH + hoff + e] = (bf16_t)hv;
            else    hf[(size_t)t * EP + e] = hv;
        }
    }
}

// ---------------- Packing (interleaved-gate layout) ----------------
// A_enc (4096 x 1152 bf16): [x(0:101) pad(101:128) h(128:1152) = 1024 elems]
// A_dec (4096 x 1152 bf16): [enc(0:1024) h(1024:1152) = 128 elems]
__global__ void pack_x(const float* __restrict__ x, bf16_t* __restrict__ Aenc)
{
    int row = blockIdx.x;      // 4096
    int cx  = threadIdx.x;     // 128
    if (cx < 101)
        Aenc[(size_t)row * 1152 + cx] = (bf16_t)x[row * 101 + cx];
}

// W_enc: per layer 4096 N-positions x 1152 cols. N-position p: eb=p>>6,
// g=(p>>4)&3, ei=p&15, e=eb*16+ei; orig row = g*1000+e (if e<1000).
// Cols: [Wih(0:101) 0 Whh(128:1128) 0]
__global__ void pack_wenc(const float* __restrict__ Wih, const float* __restrict__ Whh,
                          bf16_t* __restrict__ W)
{
    int cidx = blockIdx.x * 256 + threadIdx.x;
    int row  = blockIdx.y;             // 0..16383
    if (cidx >= 1152) return;
    int l = row >> 12, p = row & 4095;
    int g = (p >> 4) & 3, e = ((p >> 6) << 4) + (p & 15);
    float v = 0.0f;
    if (e < 1000) {
        size_t r = (size_t)l * 4000 + g * 1000 + e;
        if (cidx < 101)                       v = Wih[r * 101 + cidx];
        else if (cidx >= 128 && cidx < 1128)  v = Whh[r * 1000 + (cidx - 128)];
    }
    W[(size_t)row * 1152 + cidx] = (bf16_t)v;
}

// W_dec: per layer 512 N-positions x 1152 cols. e = (p>>6)*16 + (p&15) in
// [0,128), orig row = g*101+e (if e<101). Cols: [dWih(0:1000) 0 dWhh(1024:1125) 0]
__global__ void pack_wdec(const float* __restrict__ Wih, const float* __restrict__ Whh,
                          bf16_t* __restrict__ W)
{
    int cidx = blockIdx.x * 256 + threadIdx.x;
    int row  = blockIdx.y;             // 0..2047
    if (cidx >= 1152) return;
    int l = row >> 9, p = row & 511;
    int g = (p >> 4) & 3, e = ((p >> 6) << 4) + (p & 15);
    float v = 0.0f;
    if (e < 101) {
        size_t r = (size_t)l * 404 + g * 101 + e;
        if (cidx < 1000)                       v = Wih[r * 1000 + cidx];
        else if (cidx >= 1024 && cidx < 1125)  v = Whh[r * 101 + (cidx - 1024)];
    }
    W[(size_t)row * 1152 + cidx] = (bf16_t)v;
}

__global__ void pack_be(const float* __restrict__ bih, const float* __restrict__ bhh,
                        float* __restrict__ b)
{
    int idx = blockIdx.x * 256 + threadIdx.x;  // 16384
    int l = idx >> 12, p = idx & 4095;
    int g = (p >> 4) & 3, e = ((p >> 6) << 4) + (p & 15);
    b[idx] = (e < 1000) ? (bih[l * 4000 + g * 1000 + e] + bhh[l * 4000 + g * 1000 + e]) : 0.0f;
}

__global__ void pack_bd(const float* __restrict__ bih, const float* __restrict__ bhh,
                        float* __restrict__ b)
{
    int idx = blockIdx.x * 256 + threadIdx.x;  // 2048
    int l = idx >> 9, p = idx & 511;
    int g = (p >> 4) & 3, e = ((p >> 6) << 4) + (p & 15);
    b[idx] = (e < 101) ? (bih[l * 404 + g * 101 + e] + bhh[l * 404 + g * 101 + e]) : 0.0f;
}

// ---------------- log_softmax over 101 valid cols (stride 128) ----------------
__global__ void log_softmax_k(const float* __restrict__ h, float* __restrict__ out)
{
    int row = blockIdx.x;
    int l   = threadIdx.x;          // 64
    const float* hr = h + (size_t)row * 128;
    float v1 = (l < 101)      ? hr[l]      : -INFINITY;
    float v2 = (l + 64 < 101) ? hr[l + 64] : -INFINITY;
    float m = fmaxf(v1, v2);
#pragma unroll
    for (int off = 32; off > 0; off >>= 1) m = fmaxf(m, __shfl_down(m, off));
    m = __shfl(m, 0);
    float ev = ((l < 101) ? __expf(v1 - m) : 0.0f) + ((l + 64 < 101) ? __expf(v2 - m) : 0.0f);
#pragma unroll
    for (int off = 32; off > 0; off >>= 1) ev += __shfl_down(ev, off);
    float lse = m + __logf(__shfl(ev, 0));
    float* orow = out + (size_t)row * 101;
    if (l < 101)      orow[l]      = v1 - lse;
    if (l + 64 < 101) orow[l + 64] = v2 - lse;
}

extern "C" void kernel_launch(void* const* d_in, const int* in_sizes, int n_in,
                              void* d_out, int out_size, void* d_ws, size_t ws_size,
                              hipStream_t stream)
{
    (void)in_sizes; (void)n_in; (void)out_size; (void)ws_size;
    const float* x    = (const float*)d_in[0];
    const float* eWih = (const float*)d_in[1];
    const float* eWhh = (const float*)d_in[2];
    const float* ebih = (const float*)d_in[3];
    const float* ebhh = (const float*)d_in[4];
    const float* dWih = (const float*)d_in[5];
    const float* dWhh = (const float*)d_in[6];
    const float* dbih = (const float*)d_in[7];
    const float* dbhh = (const float*)d_in[8];

    char* ws = (char*)d_ws;
    bf16_t* Aenc = (bf16_t*)(ws);                 // 4096*1152*2   =  9,437,184
    bf16_t* Wenc = (bf16_t*)(ws + 9437184);       // 4*4096*1152*2 = 37,748,736
    bf16_t* Adec = (bf16_t*)(ws + 47185920);      //                  9,437,184
    bf16_t* Wdec = (bf16_t*)(ws + 56623104);      // 4*512*1152*2  =  4,718,592
    float*  bse  = (float*) (ws + 61341696);      // 4*4096*4      =     65,536
    float*  bsd  = (float*) (ws + 61407232);      // 4*512*4       =      8,192
    float*  cenc = (float*) (ws + 61415424);      // 4096*1024*4   = 16,777,216
    float*  cdec = (float*) (ws + 78192640);      // 4096*128*4    =   2,097,152
    float*  hdec = (float*) (ws + 80289792);      // 4096*128*4    =   2,097,152  (end 82,386,944)

    // ws re-poisoned 0xAA every call: zero A pads/h-slots and cell states.
    hipMemsetAsync(Aenc, 0, 9437184, stream);
    hipMemsetAsync(Adec, 0, 9437184, stream);
    hipMemsetAsync(cenc, 0, 16777216, stream);
    hipMemsetAsync(cdec, 0, 2097152, stream);

    pack_x   <<<4096, 128, 0, stream>>>(x, Aenc);
    pack_wenc<<<dim3(5, 16384), 256, 0, stream>>>(eWih, eWhh, Wenc);
    pack_wdec<<<dim3(5, 2048),  256, 0, stream>>>(dWih, dWhh, Wdec);
    pack_be  <<<64, 256, 0, stream>>>(ebih, ebhh, bse);
    pack_bd  <<<8,  256, 0, stream>>>(dbih, dbhh, bsd);

    // Encoder: 4 layers, fused gates-GEMM + LSTM cell.
    // Layers 0-2 write h (bf16) back into Aenc's h slot (cols 128..1151);
    // layer 3 writes relu(h) into Adec's x slot (cols 0..1023).
    for (int l = 0; l < 4; ++l) {
        gemm_lstm<<<dim3(32, 32), 256, 0, stream>>>(
            Aenc, Wenc + (size_t)l * 4096 * 1152, bse + l * 4096,
            cenc, 1024,
            (l < 3) ? Aenc : Adec, 1152, (l < 3) ? 128 : 0, nullptr,
            1152, 1152, 1152, (l == 3) ? 1 : 0);
    }
    // Decoder: 4 layers. Layers 0-2 write h into Adec cols 1024..1151;
    // layer 3 writes fp32 h into hdec (4096 x 128, cols >= 101 are zero-pad).
    for (int l = 0; l < 4; ++l) {
        gemm_lstm<<<dim3(4, 32), 256, 0, stream>>>(
            Adec, Wdec + (size_t)l * 512 * 1152, bsd + l * 512,
            cdec, 128,
            (l < 3) ? Adec : nullptr, 1152, 1024, (l == 3) ? hdec : nullptr,
            1152, 1152, 1152, 0);
    }
    log_softmax_k<<<4096, 64, 0, stream>>>(hdec, (float*)d_out);
}

// Round 3
// 472.172 us; speedup vs baseline: 1.2566x; 1.1578x over previous
//
#include <hip/hip_runtime.h>
#include <cstdint>
#include <cstddef>
#include <cmath>

typedef __bf16 bf16_t;
typedef __bf16 bf16x8 __attribute__((ext_vector_type(8)));
typedef float floatx4 __attribute__((ext_vector_type(4)));

#define AS1 __attribute__((address_space(1)))
#define AS3 __attribute__((address_space(3)))

__device__ __forceinline__ void gload_lds16(const bf16_t* g, bf16_t* l) {
    __builtin_amdgcn_global_load_lds((AS1 void*)(uintptr_t)(g), (AS3 void*)(l), 16, 0, 0);
}

__device__ __forceinline__ float sigf(float x) { return 1.0f / (1.0f + __expf(-x)); }
__device__ __forceinline__ float tanhfast(float x) { return 1.0f - 2.0f / (__expf(2.0f * x) + 1.0f); }

// ------------- Fused GEMM + LSTM cell -------------
// gates(M x N) = A(M,K) @ W(N,K)^T + bias(N), then LSTM cell per element.
// Weight rows packed interleaved (see pack_wenc): each lane's acc[i][0..3]
// are the 4 gates (i,f,g,o) of one element column e = ((n0+wn)>>2)+(lane&15).
//
// LDS bank-conflict fix: tile row stride is 128 B = exactly 32 banks, so the
// un-swizzled layout puts every row on the same banks (measured 1.4e7 conflict
// cycles/dispatch = ~33% of runtime). We XOR-swizzle 16B chunks:
//   physical_chunk = logical_kchunk ^ (row & 7)
// Staging keeps the mandatory linear base+lane*16 LDS pattern of
// global_load_lds; the *global* address per lane is permuted instead
// (still coalesced: a permutation within each 128B segment). Fragment reads
// then hit all 8 bank groups across 8 consecutive rows -> conflict-free.
__global__ __launch_bounds__(256, 4)
void gemm_lstm(const bf16_t* __restrict__ A, const bf16_t* __restrict__ B,
               const float* __restrict__ bias, float* __restrict__ c, int EP,
               bf16_t* __restrict__ hb, int ldH, int hoff, float* __restrict__ hf,
               int K, int ldA, int ldB, int relu)
{
    __shared__ bf16_t As[128 * 64];
    __shared__ bf16_t Bs[128 * 64];
    const int tid  = threadIdx.x;
    const int lane = tid & 63;
    const int w    = tid >> 6;
    const int wm   = (w & 1) * 64;
    const int wn   = (w >> 1) * 64;
    const int m0   = blockIdx.y * 128;
    const int n0   = blockIdx.x * 128;

    floatx4 zero = {0.0f, 0.0f, 0.0f, 0.0f};
    floatx4 acc[4][4];
#pragma unroll
    for (int i = 0; i < 4; ++i)
#pragma unroll
        for (int j = 0; j < 4; ++j) acc[i][j] = zero;

    const int srow = lane >> 3;                 // staging row-in-chunk 0..7
    const int sk   = ((lane & 7) ^ srow) * 8;   // swizzled k-chunk (elements)
    const int fr   = lane & 15;                 // fragment row
    const int fx   = fr & 7;                    // read-side xor key

    const bf16_t* Ag = A + (size_t)(m0 + srow) * ldA + sk;
    const bf16_t* Bg = B + (size_t)(n0 + srow) * ldB + sk;

    for (int k0 = 0; k0 < K; k0 += 64) {
        __syncthreads();
#pragma unroll
        for (int j = 0; j < 4; ++j) {
            int r0 = (w * 4 + j) * 8;           // chunk base row
            gload_lds16(Ag + (size_t)r0 * ldA + k0, As + r0 * 64 + lane * 8);
            gload_lds16(Bg + (size_t)r0 * ldB + k0, Bs + r0 * 64 + lane * 8);
        }
        __syncthreads();
#pragma unroll
        for (int kk = 0; kk < 64; kk += 32) {
            const int pc = ((((kk >> 3) + (lane >> 4)) ^ fx) << 3);
            bf16x8 af[4], bfr[4];
#pragma unroll
            for (int i = 0; i < 4; ++i)
                af[i] = *(const bf16x8*)(As + (wm + i * 16 + fr) * 64 + pc);
#pragma unroll
            for (int j = 0; j < 4; ++j)
                bfr[j] = *(const bf16x8*)(Bs + (wn + j * 16 + fr) * 64 + pc);
#pragma unroll
            for (int i = 0; i < 4; ++i)
#pragma unroll
                for (int j = 0; j < 4; ++j)
                    acc[i][j] = __builtin_amdgcn_mfma_f32_16x16x32_bf16(af[i], bfr[j], acc[i][j], 0, 0, 0);
        }
    }

    // Fused LSTM epilogue. C/D layout: col = lane&15, row = (lane>>4)*4 + reg.
    const int crow = (lane >> 4) * 4;
    const int ccol = lane & 15;
    const int e    = ((n0 + wn) >> 2) + ccol;
    float bi[4];
#pragma unroll
    for (int j = 0; j < 4; ++j) bi[j] = bias[n0 + wn + j * 16 + ccol];

#pragma unroll
    for (int i = 0; i < 4; ++i) {
#pragma unroll
        for (int r = 0; r < 4; ++r) {
            int t = m0 + wm + i * 16 + crow + r;
            float iv = acc[i][0][r] + bi[0];
            float fv = acc[i][1][r] + bi[1];
            float gv = acc[i][2][r] + bi[2];
            float ov = acc[i][3][r] + bi[3];
            size_t cix = (size_t)t * EP + e;
            float cv = sigf(fv) * c[cix] + sigf(iv) * tanhfast(gv);
            c[cix] = cv;
            float hv = sigf(ov) * tanhfast(cv);
            if (relu) hv = fmaxf(hv, 0.0f);
            if (hb) hb[(size_t)t * ldH + hoff + e] = (bf16_t)hv;
            else    hf[(size_t)t * EP + e] = hv;
        }
    }
}

// ---------------- Packing (interleaved-gate layout) ----------------
// A_enc (4096 x 1152 bf16): [x(0:101) pad(101:128) h(128:1152) = 1024 elems]
// A_dec (4096 x 1152 bf16): [enc(0:1024) h(1024:1152) = 128 elems]
__global__ void pack_x(const float* __restrict__ x, bf16_t* __restrict__ Aenc)
{
    int row = blockIdx.x;      // 4096
    int cx  = threadIdx.x;     // 128
    if (cx < 101)
        Aenc[(size_t)row * 1152 + cx] = (bf16_t)x[row * 101 + cx];
}

// W_enc: per layer 4096 N-positions x 1152 cols. N-position p: eb=p>>6,
// g=(p>>4)&3, ei=p&15, e=eb*16+ei; orig row = g*1000+e (if e<1000).
// Cols: [Wih(0:101) 0 Whh(128:1128) 0]
__global__ void pack_wenc(const float* __restrict__ Wih, const float* __restrict__ Whh,
                          bf16_t* __restrict__ W)
{
    int cidx = blockIdx.x * 256 + threadIdx.x;
    int row  = blockIdx.y;             // 0..16383
    if (cidx >= 1152) return;
    int l = row >> 12, p = row & 4095;
    int g = (p >> 4) & 3, e = ((p >> 6) << 4) + (p & 15);
    float v = 0.0f;
    if (e < 1000) {
        size_t r = (size_t)l * 4000 + g * 1000 + e;
        if (cidx < 101)                       v = Wih[r * 101 + cidx];
        else if (cidx >= 128 && cidx < 1128)  v = Whh[r * 1000 + (cidx - 128)];
    }
    W[(size_t)row * 1152 + cidx] = (bf16_t)v;
}

// W_dec: per layer 512 N-positions x 1152 cols. e = (p>>6)*16 + (p&15) in
// [0,128), orig row = g*101+e (if e<101). Cols: [dWih(0:1000) 0 dWhh(1024:1125) 0]
__global__ void pack_wdec(const float* __restrict__ Wih, const float* __restrict__ Whh,
                          bf16_t* __restrict__ W)
{
    int cidx = blockIdx.x * 256 + threadIdx.x;
    int row  = blockIdx.y;             // 0..2047
    if (cidx >= 1152) return;
    int l = row >> 9, p = row & 511;
    int g = (p >> 4) & 3, e = ((p >> 6) << 4) + (p & 15);
    float v = 0.0f;
    if (e < 101) {
        size_t r = (size_t)l * 404 + g * 101 + e;
        if (cidx < 1000)                       v = Wih[r * 1000 + cidx];
        else if (cidx >= 1024 && cidx < 1125)  v = Whh[r * 101 + (cidx - 1024)];
    }
    W[(size_t)row * 1152 + cidx] = (bf16_t)v;
}

__global__ void pack_be(const float* __restrict__ bih, const float* __restrict__ bhh,
                        float* __restrict__ b)
{
    int idx = blockIdx.x * 256 + threadIdx.x;  // 16384
    int l = idx >> 12, p = idx & 4095;
    int g = (p >> 4) & 3, e = ((p >> 6) << 4) + (p & 15);
    b[idx] = (e < 1000) ? (bih[l * 4000 + g * 1000 + e] + bhh[l * 4000 + g * 1000 + e]) : 0.0f;
}

__global__ void pack_bd(const float* __restrict__ bih, const float* __restrict__ bhh,
                        float* __restrict__ b)
{
    int idx = blockIdx.x * 256 + threadIdx.x;  // 2048
    int l = idx >> 9, p = idx & 511;
    int g = (p >> 4) & 3, e = ((p >> 6) << 4) + (p & 15);
    b[idx] = (e < 101) ? (bih[l * 404 + g * 101 + e] + bhh[l * 404 + g * 101 + e]) : 0.0f;
}

// ---------------- log_softmax over 101 valid cols (stride 128) ----------------
__global__ void log_softmax_k(const float* __restrict__ h, float* __restrict__ out)
{
    int row = blockIdx.x;
    int l   = threadIdx.x;          // 64
    const float* hr = h + (size_t)row * 128;
    float v1 = (l < 101)      ? hr[l]      : -INFINITY;
    float v2 = (l + 64 < 101) ? hr[l + 64] : -INFINITY;
    float m = fmaxf(v1, v2);
#pragma unroll
    for (int off = 32; off > 0; off >>= 1) m = fmaxf(m, __shfl_down(m, off));
    m = __shfl(m, 0);
    float ev = ((l < 101) ? __expf(v1 - m) : 0.0f) + ((l + 64 < 101) ? __expf(v2 - m) : 0.0f);
#pragma unroll
    for (int off = 32; off > 0; off >>= 1) ev += __shfl_down(ev, off);
    float lse = m + __logf(__shfl(ev, 0));
    float* orow = out + (size_t)row * 101;
    if (l < 101)      orow[l]      = v1 - lse;
    if (l + 64 < 101) orow[l + 64] = v2 - lse;
}

extern "C" void kernel_launch(void* const* d_in, const int* in_sizes, int n_in,
                              void* d_out, int out_size, void* d_ws, size_t ws_size,
                              hipStream_t stream)
{
    (void)in_sizes; (void)n_in; (void)out_size; (void)ws_size;
    const float* x    = (const float*)d_in[0];
    const float* eWih = (const float*)d_in[1];
    const float* eWhh = (const float*)d_in[2];
    const float* ebih = (const float*)d_in[3];
    const float* ebhh = (const float*)d_in[4];
    const float* dWih = (const float*)d_in[5];
    const float* dWhh = (const float*)d_in[6];
    const float* dbih = (const float*)d_in[7];
    const float* dbhh = (const float*)d_in[8];

    char* ws = (char*)d_ws;
    bf16_t* Aenc = (bf16_t*)(ws);                 // 4096*1152*2   =  9,437,184
    bf16_t* Wenc = (bf16_t*)(ws + 9437184);       // 4*4096*1152*2 = 37,748,736
    bf16_t* Adec = (bf16_t*)(ws + 47185920);      //                  9,437,184
    bf16_t* Wdec = (bf16_t*)(ws + 56623104);      // 4*512*1152*2  =  4,718,592
    float*  bse  = (float*) (ws + 61341696);      // 4*4096*4      =     65,536
    float*  bsd  = (float*) (ws + 61407232);      // 4*512*4       =      8,192
    float*  cenc = (float*) (ws + 61415424);      // 4096*1024*4   = 16,777,216
    float*  cdec = (float*) (ws + 78192640);      // 4096*128*4    =   2,097,152
    float*  hdec = (float*) (ws + 80289792);      // 4096*128*4    =   2,097,152  (end 82,386,944)

    // ws re-poisoned 0xAA every call: zero A pads/h-slots and cell states.
    hipMemsetAsync(Aenc, 0, 9437184, stream);
    hipMemsetAsync(Adec, 0, 9437184, stream);
    hipMemsetAsync(cenc, 0, 16777216, stream);
    hipMemsetAsync(cdec, 0, 2097152, stream);

    pack_x   <<<4096, 128, 0, stream>>>(x, Aenc);
    pack_wenc<<<dim3(5, 16384), 256, 0, stream>>>(eWih, eWhh, Wenc);
    pack_wdec<<<dim3(5, 2048),  256, 0, stream>>>(dWih, dWhh, Wdec);
    pack_be  <<<64, 256, 0, stream>>>(ebih, ebhh, bse);
    pack_bd  <<<8,  256, 0, stream>>>(dbih, dbhh, bsd);

    // Encoder: 4 layers, fused gates-GEMM + LSTM cell.
    for (int l = 0; l < 4; ++l) {
        gemm_lstm<<<dim3(32, 32), 256, 0, stream>>>(
            Aenc, Wenc + (size_t)l * 4096 * 1152, bse + l * 4096,
            cenc, 1024,
            (l < 3) ? Aenc : Adec, 1152, (l < 3) ? 128 : 0, nullptr,
            1152, 1152, 1152, (l == 3) ? 1 : 0);
    }
    // Decoder: 4 layers.
    for (int l = 0; l < 4; ++l) {
        gemm_lstm<<<dim3(4, 32), 256, 0, stream>>>(
            Adec, Wdec + (size_t)l * 512 * 1152, bsd + l * 512,
            cdec, 128,
            (l < 3) ? Adec : nullptr, 1152, 1024, (l == 3) ? hdec : nullptr,
            1152, 1152, 1152, 0);
    }
    log_softmax_k<<<4096, 64, 0, stream>>>(hdec, (float*)d_out);
}

// Round 4
// 407.734 us; speedup vs baseline: 1.4552x; 1.1580x over previous
//
#include <hip/hip_runtime.h>
#include <cstdint>
#include <cstddef>
#include <cmath>

typedef __bf16 bf16_t;
typedef __bf16 bf16x8 __attribute__((ext_vector_type(8)));
typedef float floatx4 __attribute__((ext_vector_type(4)));

#define AS1 __attribute__((address_space(1)))
#define AS3 __attribute__((address_space(3)))

__device__ __forceinline__ void gload_lds16(const bf16_t* g, bf16_t* l) {
    __builtin_amdgcn_global_load_lds((AS1 void*)(uintptr_t)(g), (AS3 void*)(l), 16, 0, 0);
}

__device__ __forceinline__ float sigf(float x) { return 1.0f / (1.0f + __expf(-x)); }
__device__ __forceinline__ float tanhfast(float x) { return 1.0f - 2.0f / (__expf(2.0f * x) + 1.0f); }

// ------------- Fused GEMM + LSTM cell (templated M-tile) -------------
// gates(M x N) = A(M,K) @ W(N,K)^T + bias(N), then LSTM cell per element.
// Weight rows packed gate-interleaved: each lane's acc[i][0..3] are the 4
// gates (i,f,g,o) of one element column e = ((n0+wn)>>2)+(lane&15).
// LDS XOR swizzle (R2): physical 16B chunk = logical_kchunk ^ (row&7);
// staging keeps the mandatory linear base+lane*16 global_load_lds pattern by
// permuting the per-lane *global* address (still intra-128B-segment coalesced).
// BM=128 for encoder (grid 32x32); BM=64 for decoder (grid 4x64, 2x blocks
// to cover all 256 CUs since N=512 only gives 4 N-tiles).
template<int BM>
__global__ __launch_bounds__(256, 4)
void gemm_lstm(const bf16_t* __restrict__ A, const bf16_t* __restrict__ B,
               const float* __restrict__ bias, float* __restrict__ c, int EP,
               bf16_t* __restrict__ hb, int ldH, int hoff, float* __restrict__ hf,
               int K, int ldA, int ldB, int relu)
{
    constexpr int AI = BM / 32;          // i-frags per wave = A-chunks per thread
    __shared__ bf16_t As[BM * 64];
    __shared__ bf16_t Bs[128 * 64];
    const int tid  = threadIdx.x;
    const int lane = tid & 63;
    const int w    = tid >> 6;
    const int wm   = (w & 1) * (BM / 2);
    const int wn   = (w >> 1) * 64;
    const int m0   = blockIdx.y * BM;
    const int n0   = blockIdx.x * 128;

    floatx4 zero = {0.0f, 0.0f, 0.0f, 0.0f};
    floatx4 acc[AI][4];
#pragma unroll
    for (int i = 0; i < AI; ++i)
#pragma unroll
        for (int j = 0; j < 4; ++j) acc[i][j] = zero;

    const int srow = lane >> 3;                 // staging row-in-chunk 0..7
    const int sk   = ((lane & 7) ^ srow) * 8;   // swizzled k-chunk (elements)
    const int fr   = lane & 15;                 // fragment row
    const int fx   = fr & 7;                    // read-side xor key

    const bf16_t* Ag = A + (size_t)(m0 + srow) * ldA + sk;
    const bf16_t* Bg = B + (size_t)(n0 + srow) * ldB + sk;

    for (int k0 = 0; k0 < K; k0 += 64) {
        __syncthreads();
#pragma unroll
        for (int j = 0; j < AI; ++j) {
            int r0 = (w * AI + j) * 8;
            gload_lds16(Ag + (size_t)r0 * ldA + k0, As + r0 * 64 + lane * 8);
        }
#pragma unroll
        for (int j = 0; j < 4; ++j) {
            int r0 = (w * 4 + j) * 8;
            gload_lds16(Bg + (size_t)r0 * ldB + k0, Bs + r0 * 64 + lane * 8);
        }
        __syncthreads();
#pragma unroll
        for (int kk = 0; kk < 64; kk += 32) {
            const int pc = ((((kk >> 3) + (lane >> 4)) ^ fx) << 3);
            bf16x8 af[AI], bfr[4];
#pragma unroll
            for (int i = 0; i < AI; ++i)
                af[i] = *(const bf16x8*)(As + (wm + i * 16 + fr) * 64 + pc);
#pragma unroll
            for (int j = 0; j < 4; ++j)
                bfr[j] = *(const bf16x8*)(Bs + (wn + j * 16 + fr) * 64 + pc);
#pragma unroll
            for (int i = 0; i < AI; ++i)
#pragma unroll
                for (int j = 0; j < 4; ++j)
                    acc[i][j] = __builtin_amdgcn_mfma_f32_16x16x32_bf16(af[i], bfr[j], acc[i][j], 0, 0, 0);
        }
    }

    // Fused LSTM epilogue. C/D layout: col = lane&15, row = (lane>>4)*4 + reg.
    const int crow = (lane >> 4) * 4;
    const int ccol = lane & 15;
    const int e    = ((n0 + wn) >> 2) + ccol;
    float bi[4];
#pragma unroll
    for (int j = 0; j < 4; ++j) bi[j] = bias[n0 + wn + j * 16 + ccol];

#pragma unroll
    for (int i = 0; i < AI; ++i) {
#pragma unroll
        for (int r = 0; r < 4; ++r) {
            int t = m0 + wm + i * 16 + crow + r;
            float iv = acc[i][0][r] + bi[0];
            float fv = acc[i][1][r] + bi[1];
            float gv = acc[i][2][r] + bi[2];
            float ov = acc[i][3][r] + bi[3];
            size_t cix = (size_t)t * EP + e;
            float cv = sigf(fv) * c[cix] + sigf(iv) * tanhfast(gv);
            c[cix] = cv;
            float hv = sigf(ov) * tanhfast(cv);
            if (relu) hv = fmaxf(hv, 0.0f);
            if (hb) hb[(size_t)t * ldH + hoff + e] = (bf16_t)hv;
            else    hf[(size_t)t * EP + e] = hv;
        }
    }
}

// ---------------- Packing (interleaved-gate layout, vectorized) ----------------
// A_enc (4096 x 1152 bf16): [x(0:101) pad(101:128) h(128:1152)]
// A_dec (4096 x 1152 bf16): [enc(0:1024) h(1024:1152)]

// Fills ALL of Aenc: x into cols 0..100, zeros elsewhere (pad + h-slot).
// One thread per 8 cols: 4096 rows * 144 groups = 589824 threads.
__global__ void pack_xz(const float* __restrict__ x, bf16_t* __restrict__ Aenc)
{
    int gid = blockIdx.x * 256 + threadIdx.x;
    int row = gid / 144, grp = gid - row * 144;
    int c0  = grp * 8;
    float v[8];
#pragma unroll
    for (int u = 0; u < 8; ++u) v[u] = 0.0f;
    if (c0 < 101) {
        const float* src = x + (size_t)row * 101;
#pragma unroll
        for (int u = 0; u < 8; ++u) { int cc = c0 + u; if (cc < 101) v[u] = src[cc]; }
    }
    bf16x8 o;
#pragma unroll
    for (int u = 0; u < 8; ++u) o[u] = (bf16_t)v[u];
    *(bf16x8*)(Aenc + (size_t)row * 1152 + c0) = o;
}

// W_enc: per layer 4096 N-positions x 1152 cols. N-pos p: g=(p>>4)&3,
// e=((p>>6)<<4)+(p&15); orig row = g*1000+e (if e<1000).
// Cols: [Wih(0:101) 0 Whh(128:1128) 0]. 16384 rows * 144 groups of 8.
__global__ void pack_wenc(const float* __restrict__ Wih, const float* __restrict__ Whh,
                          bf16_t* __restrict__ W)
{
    int gid = blockIdx.x * 256 + threadIdx.x;
    int row = gid / 144, grp = gid - row * 144;
    int l = row >> 12, p = row & 4095;
    int g = (p >> 4) & 3, e = ((p >> 6) << 4) + (p & 15);
    int c0 = grp * 8;
    float v[8];
#pragma unroll
    for (int u = 0; u < 8; ++u) v[u] = 0.0f;
    if (e < 1000) {
        size_t r = (size_t)l * 4000 + g * 1000 + e;
        if (c0 >= 128 && c0 < 1128) {
            // Whh row stride 1000 (mult of 4) and c0-128 mult of 8 -> 16B aligned
            const float* src = Whh + r * 1000 + (c0 - 128);
            float4 a = *(const float4*)src;
            float4 b = *(const float4*)(src + 4);
            v[0]=a.x; v[1]=a.y; v[2]=a.z; v[3]=a.w; v[4]=b.x; v[5]=b.y; v[6]=b.z; v[7]=b.w;
        } else if (c0 < 128) {
            const float* src = Wih + r * 101;
#pragma unroll
            for (int u = 0; u < 8; ++u) { int cc = c0 + u; if (cc < 101) v[u] = src[cc]; }
        }
    }
    bf16x8 o;
#pragma unroll
    for (int u = 0; u < 8; ++u) o[u] = (bf16_t)v[u];
    *(bf16x8*)(W + (size_t)row * 1152 + c0) = o;
}

// W_dec: per layer 512 N-positions x 1152 cols. e in [0,128); orig row =
// g*101+e (if e<101). Cols: [dWih(0:1000) 0 dWhh(1024:1125) 0].
// 2048 rows * 144 groups of 8.
__global__ void pack_wdec(const float* __restrict__ Wih, const float* __restrict__ Whh,
                          bf16_t* __restrict__ W)
{
    int gid = blockIdx.x * 256 + threadIdx.x;
    int row = gid / 144, grp = gid - row * 144;
    int l = row >> 9, p = row & 511;
    int g = (p >> 4) & 3, e = ((p >> 6) << 4) + (p & 15);
    int c0 = grp * 8;
    float v[8];
#pragma unroll
    for (int u = 0; u < 8; ++u) v[u] = 0.0f;
    if (e < 101) {
        size_t r = (size_t)l * 404 + g * 101 + e;
        if (c0 < 1000) {  // c0 mult of 8 and <1000 -> c0<=992, full 8 in range
            const float* src = Wih + r * 1000 + c0;
            float4 a = *(const float4*)src;
            float4 b = *(const float4*)(src + 4);
            v[0]=a.x; v[1]=a.y; v[2]=a.z; v[3]=a.w; v[4]=b.x; v[5]=b.y; v[6]=b.z; v[7]=b.w;
        } else if (c0 >= 1024 && c0 < 1128) {
            const float* src = Whh + r * 101;
#pragma unroll
            for (int u = 0; u < 8; ++u) { int cc = c0 + u; if (cc < 1125) v[u] = src[cc - 1024]; }
        }
    }
    bf16x8 o;
#pragma unroll
    for (int u = 0; u < 8; ++u) o[u] = (bf16_t)v[u];
    *(bf16x8*)(W + (size_t)row * 1152 + c0) = o;
}

// Fused bias pack: bse (16384) then bsd (2048). 18432 threads = 72 blocks.
__global__ void pack_b(const float* __restrict__ ebih, const float* __restrict__ ebhh,
                       const float* __restrict__ dbih, const float* __restrict__ dbhh,
                       float* __restrict__ bse, float* __restrict__ bsd)
{
    int idx = blockIdx.x * 256 + threadIdx.x;
    if (idx < 16384) {
        int l = idx >> 12, p = idx & 4095;
        int g = (p >> 4) & 3, e = ((p >> 6) << 4) + (p & 15);
        bse[idx] = (e < 1000) ? (ebih[l * 4000 + g * 1000 + e] + ebhh[l * 4000 + g * 1000 + e]) : 0.0f;
    } else {
        int k = idx - 16384;
        int l = k >> 9, p = k & 511;
        int g = (p >> 4) & 3, e = ((p >> 6) << 4) + (p & 15);
        bsd[k] = (e < 101) ? (dbih[l * 404 + g * 101 + e] + dbhh[l * 404 + g * 101 + e]) : 0.0f;
    }
}

// Zero cenc (4096x1024 f32) + cdec (4096x128 f32) + Adec h-slot (cols
// 1024..1151, 16 x 16B per row). 16B stores; 1,245,184 chunks = 4864 blocks.
__global__ void zero_misc(float* __restrict__ cenc, float* __restrict__ cdec,
                          bf16_t* __restrict__ Adec)
{
    int gid = blockIdx.x * 256 + threadIdx.x;
    float4 z = {0.0f, 0.0f, 0.0f, 0.0f};
    if (gid < 1048576) {
        ((float4*)cenc)[gid] = z;
    } else if (gid < 1179648) {
        ((float4*)cdec)[gid - 1048576] = z;
    } else {
        int k = gid - 1179648;           // 0..65535
        int row = k >> 4, off = (k & 15) * 8;
        *(float4*)(Adec + (size_t)row * 1152 + 1024 + off) = z;
    }
}

// ---------------- log_softmax over 101 valid cols (stride 128) ----------------
__global__ void log_softmax_k(const float* __restrict__ h, float* __restrict__ out)
{
    int row = blockIdx.x;
    int l   = threadIdx.x;          // 64
    const float* hr = h + (size_t)row * 128;
    float v1 = (l < 101)      ? hr[l]      : -INFINITY;
    float v2 = (l + 64 < 101) ? hr[l + 64] : -INFINITY;
    float m = fmaxf(v1, v2);
#pragma unroll
    for (int off = 32; off > 0; off >>= 1) m = fmaxf(m, __shfl_down(m, off));
    m = __shfl(m, 0);
    float ev = ((l < 101) ? __expf(v1 - m) : 0.0f) + ((l + 64 < 101) ? __expf(v2 - m) : 0.0f);
#pragma unroll
    for (int off = 32; off > 0; off >>= 1) ev += __shfl_down(ev, off);
    float lse = m + __logf(__shfl(ev, 0));
    float* orow = out + (size_t)row * 101;
    if (l < 101)      orow[l]      = v1 - lse;
    if (l + 64 < 101) orow[l + 64] = v2 - lse;
}

extern "C" void kernel_launch(void* const* d_in, const int* in_sizes, int n_in,
                              void* d_out, int out_size, void* d_ws, size_t ws_size,
                              hipStream_t stream)
{
    (void)in_sizes; (void)n_in; (void)out_size; (void)ws_size;
    const float* x    = (const float*)d_in[0];
    const float* eWih = (const float*)d_in[1];
    const float* eWhh = (const float*)d_in[2];
    const float* ebih = (const float*)d_in[3];
    const float* ebhh = (const float*)d_in[4];
    const float* dWih = (const float*)d_in[5];
    const float* dWhh = (const float*)d_in[6];
    const float* dbih = (const float*)d_in[7];
    const float* dbhh = (const float*)d_in[8];

    char* ws = (char*)d_ws;
    bf16_t* Aenc = (bf16_t*)(ws);                 // 4096*1152*2   =  9,437,184
    bf16_t* Wenc = (bf16_t*)(ws + 9437184);       // 4*4096*1152*2 = 37,748,736
    bf16_t* Adec = (bf16_t*)(ws + 47185920);      //                  9,437,184
    bf16_t* Wdec = (bf16_t*)(ws + 56623104);      // 4*512*1152*2  =  4,718,592
    float*  bse  = (float*) (ws + 61341696);      // 4*4096*4      =     65,536
    float*  bsd  = (float*) (ws + 61407232);      // 4*512*4       =      8,192
    float*  cenc = (float*) (ws + 61415424);      // 4096*1024*4   = 16,777,216
    float*  cdec = (float*) (ws + 78192640);      // 4096*128*4    =   2,097,152
    float*  hdec = (float*) (ws + 80289792);      // 4096*128*4    =   2,097,152  (end 82,386,944)

    // ws re-poisoned 0xAA every call. Aenc fully written by pack_xz; Adec
    // cols 0..1023 fully written by enc layer 3, h-slot zeroed by zero_misc.
    zero_misc<<<4864, 256, 0, stream>>>(cenc, cdec, Adec);
    pack_xz  <<<2304, 256, 0, stream>>>(x, Aenc);
    pack_wenc<<<9216, 256, 0, stream>>>(eWih, eWhh, Wenc);
    pack_wdec<<<1152, 256, 0, stream>>>(dWih, dWhh, Wdec);
    pack_b   <<<72,   256, 0, stream>>>(ebih, ebhh, dbih, dbhh, bse, bsd);

    // Encoder: 4 layers, fused gates-GEMM + LSTM cell (BM=128, 1024 blocks).
    for (int l = 0; l < 4; ++l) {
        gemm_lstm<128><<<dim3(32, 32), 256, 0, stream>>>(
            Aenc, Wenc + (size_t)l * 4096 * 1152, bse + l * 4096,
            cenc, 1024,
            (l < 3) ? Aenc : Adec, 1152, (l < 3) ? 128 : 0, nullptr,
            1152, 1152, 1152, (l == 3) ? 1 : 0);
    }
    // Decoder: 4 layers (BM=64 -> 256 blocks: N=512 gives only 4 N-tiles).
    for (int l = 0; l < 4; ++l) {
        gemm_lstm<64><<<dim3(4, 64), 256, 0, stream>>>(
            Adec, Wdec + (size_t)l * 512 * 1152, bsd + l * 512,
            cdec, 128,
            (l < 3) ? Adec : nullptr, 1152, 1024, (l == 3) ? hdec : nullptr,
            1152, 1152, 1152, 0);
    }
    log_softmax_k<<<4096, 64, 0, stream>>>(hdec, (float*)d_out);
}